// Round 8
// baseline (457.566 us; speedup 1.0000x reference)
//
#include <hip/hip_runtime.h>
#include <hip/hip_bf16.h>
#include <stdint.h>

typedef unsigned short u16;
typedef __bf16 bf16x8 __attribute__((ext_vector_type(8)));
typedef float f32x4 __attribute__((ext_vector_type(4)));
typedef unsigned int u32x4 __attribute__((ext_vector_type(4)));

#define FEAT 512
#define BATCH 8192
#define NC1 20
#define NC2 100
#define NC3 500
#define NC4 2000
#define NC5 10000
#define NCAT 2620
#define LDP 2624          // padded leading dim for pcat (16B-clean bf16 rows)
#define NTOT 12620
#define WN_BLOCKS 3155    // ceil(12620 / 4) wnorm blocks (4 rows x 64 lanes)
#define CAST_BLOCKS 2048  // 8192*512/8/256

__device__ inline u16 f2bf(float f) {
    unsigned int u = __builtin_bit_cast(unsigned int, f);
    unsigned int r = (u + 0x7FFFu + ((u >> 16) & 1u)) >> 16;
    return (u16)r;
}
__device__ inline float bfu(u16 u) {
    return __builtin_bit_cast(float, (unsigned int)u << 16);
}

__device__ inline float waveReduceSum(float v) {
    #pragma unroll
    for (int off = 32; off > 0; off >>= 1) v += __shfl_xor(v, off);
    return v;
}
__device__ inline float waveReduceMax(float v) {
    #pragma unroll
    for (int off = 32; off > 0; off >>= 1) v = fmaxf(v, __shfl_xor(v, off));
    return v;
}
__device__ inline float blockReduceSum(float v, float* sh) {
    int t = threadIdx.x;
    v = waveReduceSum(v);
    __syncthreads();
    if ((t & 63) == 0) sh[t >> 6] = v;
    __syncthreads();
    return sh[0] + sh[1] + sh[2] + sh[3];
}
__device__ inline float blockReduceMax(float v, float* sh) {
    int t = threadIdx.x;
    v = waveReduceMax(v);
    __syncthreads();
    if ((t & 63) == 0) sh[t >> 6] = v;
    __syncthreads();
    return fmaxf(fmaxf(sh[0], sh[1]), fmaxf(sh[2], sh[3]));
}

__device__ inline void gload16(const void* g, void* l) {
    __builtin_amdgcn_global_load_lds((const __attribute__((address_space(1))) void*)g,
                                     (__attribute__((address_space(3))) void*)l, 16, 0, 0);
}

// ---------------- prep: cast x to bf16 + l2-normalize all weights ----------------

__global__ __launch_bounds__(256) void prep(const float* __restrict__ x, u16* __restrict__ xb,
                                            const float* __restrict__ W1, const float* __restrict__ b1,
                                            const float* __restrict__ W2, const float* __restrict__ b2,
                                            const float* __restrict__ W3, const float* __restrict__ b3,
                                            const float* __restrict__ W4, const float* __restrict__ b4,
                                            const float* __restrict__ W5, const float* __restrict__ b5,
                                            u16* __restrict__ wb, float* __restrict__ biascat) {
    int bid = blockIdx.x;
    if (bid < WN_BLOCKS) {
        int r = bid * 4 + (threadIdx.x >> 6);
        if (r >= NTOT) return;
        int t = threadIdx.x & 63;
        const float* W; const float* b; int lr;
        if      (r < 20)   { W = W1; b = b1; lr = r; }
        else if (r < 120)  { W = W2; b = b2; lr = r - 20; }
        else if (r < 620)  { W = W3; b = b3; lr = r - 120; }
        else if (r < 2620) { W = W4; b = b4; lr = r - 620; }
        else               { W = W5; b = b5; lr = r - 2620; }
        const float* p = W + (size_t)lr * FEAT + t * 8;
        float v[8]; float ss = 0.f;
        #pragma unroll
        for (int j = 0; j < 8; ++j) { v[j] = p[j]; ss += v[j] * v[j]; }
        ss = waveReduceSum(ss);
        float inv = 1.0f / fmaxf(sqrtf(ss), 1e-12f);
        union { u16 u[8]; uint4 q; } o;
        #pragma unroll
        for (int j = 0; j < 8; ++j) o.u[j] = f2bf(v[j] * inv);
        ((uint4*)(wb + (size_t)r * FEAT))[t] = o.q;
        if (t == 0) biascat[r] = b[lr];
    } else {
        int i = (bid - WN_BLOCKS) * 256 + threadIdx.x;
        const float* p = x + (size_t)i * 8;
        union { u16 u[8]; uint4 v; } o;
        #pragma unroll
        for (int j = 0; j < 8; ++j) o.u[j] = f2bf(p[j]);
        ((uint4*)xb)[i] = o.v;
    }
}

// ---------------- GEMM over all 12620 columns ----------------
// 128x256 tile, 8 waves (2 row x 4 col), wave tile 64x64 (acc = 64 VGPR), BK=32,
// double-buffered global_load_lds w16 (48 KB LDS -> 2 blocks/CU at 4 waves/SIMD),
// blk-major LDS layout (conflict-free without XOR), counted-vmcnt raw-barrier
// pipeline, setprio around MFMA. cols < NCAT -> pcat; cols >= NCAT -> l5b
// + per-(row, coltile) softmax partials (by >= 10).

#define BM 128
#define BN 256
#define BK 32
#define KITERS (FEAT / BK)          // 16
#define CHUNKS ((BM + BN) * BK / 8) // 1536 16B chunks per stage

__global__ __launch_bounds__(512, 4) void gemm_all(const u16* __restrict__ A, const u16* __restrict__ Bw,
                                                   const float* __restrict__ bias,
                                                   u16* __restrict__ pcat, u16* __restrict__ l5b,
                                                   float* __restrict__ pmax, float* __restrict__ psum) {
    __shared__ u16 sAB[2][(BM + BN) * BK];     // 2 x 24 KB double buffer
    const int t = threadIdx.x;
    const int lane = t & 63, wid = t >> 6;
    const int lane15 = lane & 15, q = lane >> 4;
    const int wrow = wid >> 2, wcol = wid & 3;

    // XCD-aware bijective swizzle (nwg = 64*50 = 3200, %8 == 0)
    int nwg = gridDim.x * gridDim.y;
    int lid = blockIdx.y * gridDim.x + blockIdx.x;
    int cpx = nwg >> 3;
    int swz = (lid & 7) * cpx + (lid >> 3);
    int bx = swz % gridDim.x, by = swz / gridDim.x;
    const int r0 = bx * BM, c0 = by * BN;

    f32x4 acc[4][4];
    #pragma unroll
    for (int m = 0; m < 4; ++m)
        #pragma unroll
        for (int n = 0; n < 4; ++n) acc[m][n] = f32x4{0.f, 0.f, 0.f, 0.f};

    // blk-major LDS: A slots [0,512): slot = blk*128 + row; B slots [512,1536):
    // slot = 512 + blk*256 + row. Stage chunk c -> slot c (linear dest).
    auto stage = [&](int kt, int buf) {
        char* base = (char*)sAB[buf];
        #pragma unroll
        for (int p = 0; p < 3; ++p) {
            int c = p * 512 + t;                // 0..1535
            const u16* g;
            if (p == 0) {                       // A region: c in [0,512)
                int row = c & 127, blk = c >> 7;
                g = A + (size_t)(r0 + row) * FEAT + kt + blk * 8;
            } else {                            // B region: c in [512,1536)
                int cc = c - 512;
                int row = cc & 255, blk = cc >> 8;
                int brow = c0 + row; if (brow >= NTOT) brow = NTOT - 1;
                g = Bw + (size_t)brow * FEAT + kt + blk * 8;
            }
            gload16(g, base + (size_t)c * 16);
        }
    };

    stage(0, 0);            // 3 loads/thread in flight
    stage(BK, 1);           // 6 in flight
    for (int ki = 0; ki < KITERS; ++ki) {
        if (ki + 1 < KITERS) { asm volatile("s_waitcnt vmcnt(3)" ::: "memory"); }
        else                 { asm volatile("s_waitcnt vmcnt(0)" ::: "memory"); }
        __builtin_amdgcn_sched_barrier(0);
        __builtin_amdgcn_s_barrier();
        __builtin_amdgcn_sched_barrier(0);
        char* base = (char*)sAB[ki & 1];
        bf16x8 af[4], bv[4];
        #pragma unroll
        for (int m = 0; m < 4; ++m) {
            int row = wrow * 64 + m * 16 + lane15;
            af[m] = *reinterpret_cast<const bf16x8*>(base + q * 2048 + row * 16);
        }
        #pragma unroll
        for (int n = 0; n < 4; ++n) {
            int row = wcol * 64 + n * 16 + lane15;
            bv[n] = *reinterpret_cast<const bf16x8*>(base + 8192 + q * 4096 + row * 16);
        }
        __builtin_amdgcn_s_setprio(1);
        #pragma unroll
        for (int m = 0; m < 4; ++m)
            #pragma unroll
            for (int n = 0; n < 4; ++n)
                acc[m][n] = __builtin_amdgcn_mfma_f32_16x16x32_bf16(bv[n], af[m], acc[m][n], 0, 0, 0);
        __builtin_amdgcn_s_setprio(0);
        __builtin_amdgcn_sched_barrier(0);
        __builtin_amdgcn_s_barrier();
        __builtin_amdgcn_sched_barrier(0);
        if (ki + 2 < KITERS) stage((ki + 2) * BK, ki & 1);
    }

    // transposed D layout: lane holds row = r0+wrow*64+m*16+lane15,
    // cols cb..cb+3 with cb = c0+wcol*64+n*16+q*4 (fragment never spans
    // the pcat/l5 boundary since NCAT % 4 == 0)
    bool vld[4], svld[4]; int cb[4];
    #pragma unroll
    for (int n = 0; n < 4; ++n) {
        cb[n] = c0 + wcol * 64 + n * 16 + q * 4;
        vld[n] = (cb[n] < NTOT);
        svld[n] = vld[n] && (cb[n] >= NCAT);
        if (vld[n]) {
            float b0 = bias[cb[n]], b1 = bias[cb[n] + 1], b2 = bias[cb[n] + 2], b3 = bias[cb[n] + 3];
            #pragma unroll
            for (int m = 0; m < 4; ++m) {
                acc[m][n][0] += b0; acc[m][n][1] += b1;
                acc[m][n][2] += b2; acc[m][n][3] += b3;
            }
        }
    }

    if (by >= 10) {   // col-tile overlaps the l5 region: emit softmax partials
        float* fmx = (float*)sAB;            // [128][4] row-max per wcol
        float* fsm = fmx + 512;              // [128][4] row-sumexp per wcol
        float bm[4];
        #pragma unroll
        for (int m = 0; m < 4; ++m) {
            float v = -1e30f;
            #pragma unroll
            for (int n = 0; n < 4; ++n)
                if (svld[n]) {
                    #pragma unroll
                    for (int j = 0; j < 4; ++j) v = fmaxf(v, acc[m][n][j]);
                }
            v = fmaxf(v, __shfl_xor(v, 16));
            v = fmaxf(v, __shfl_xor(v, 32));
            bm[m] = v;
        }
        if (lane < 16) {
            #pragma unroll
            for (int m = 0; m < 4; ++m)
                fmx[(wrow * 64 + m * 16 + lane15) * 4 + wcol] = bm[m];
        }
        __syncthreads();
        #pragma unroll
        for (int m = 0; m < 4; ++m) {
            int row = wrow * 64 + m * 16 + lane15;
            bm[m] = fmaxf(fmaxf(fmx[row * 4], fmx[row * 4 + 1]),
                          fmaxf(fmx[row * 4 + 2], fmx[row * 4 + 3]));
        }
        float sm[4];
        #pragma unroll
        for (int m = 0; m < 4; ++m) {
            float s = 0.f;
            #pragma unroll
            for (int n = 0; n < 4; ++n)
                if (svld[n]) {
                    #pragma unroll
                    for (int j = 0; j < 4; ++j) s += __expf(acc[m][n][j] - bm[m]);
                }
            s += __shfl_xor(s, 16);
            s += __shfl_xor(s, 32);
            sm[m] = s;
        }
        if (lane < 16) {
            #pragma unroll
            for (int m = 0; m < 4; ++m)
                fsm[(wrow * 64 + m * 16 + lane15) * 4 + wcol] = sm[m];
        }
        __syncthreads();
        if (t < 128) {
            float m4 = fmaxf(fmaxf(fmx[t * 4], fmx[t * 4 + 1]), fmaxf(fmx[t * 4 + 2], fmx[t * 4 + 3]));
            float s4 = fsm[t * 4] + fsm[t * 4 + 1] + fsm[t * 4 + 2] + fsm[t * 4 + 3];
            size_t idx = (size_t)(r0 + t) * 40 + (by - 10);
            pmax[idx] = m4;
            psum[idx] = s4;
        }
    }

    // store bf16 as uint2 (4 consecutive cols per lane), routed per region
    #pragma unroll
    for (int m = 0; m < 4; ++m) {
        int row = r0 + wrow * 64 + m * 16 + lane15;
        #pragma unroll
        for (int n = 0; n < 4; ++n) {
            if (vld[n]) {
                union { u16 u[4]; uint2 v; } pk;
                #pragma unroll
                for (int j = 0; j < 4; ++j) pk.u[j] = f2bf(acc[m][n][j]);
                u16* dst = (cb[n] < NCAT)
                    ? &pcat[(size_t)row * LDP + cb[n]]
                    : &l5b[(size_t)row * NC5 + (cb[n] - NCAT)];
                *reinterpret_cast<uint2*>(dst) = pk.v;
            }
        }
    }
}

// ---------------- fused LSE + CE + probabilities + all JSDs (block per row) ----------------

__global__ __launch_bounds__(256) void probs_all(const u16* __restrict__ l5b, float* __restrict__ out,
                                                 const u16* __restrict__ pcat,
                                                 const float* __restrict__ pmax, const float* __restrict__ psum,
                                                 int nct, const int* __restrict__ tgt,
                                                 float* __restrict__ cerow,
                                                 float* __restrict__ j12, float* __restrict__ j23,
                                                 float* __restrict__ j34, float* __restrict__ j45) {
    __shared__ u16 P5[NC5];
    __shared__ float PC[LDP];
    __shared__ float sh[4];
    __shared__ float shls;
    int b = blockIdx.x, t = threadIdx.x;
    float* orow = out + (size_t)b * NC5;
    const u16* lrow = l5b + (size_t)b * NC5;
    const u16* prow = pcat + (size_t)b * LDP;

    // wave 0: reduce the per-coltile partials into the row LSE
    if (t < 64) {
        float pm = (t < nct) ? pmax[(size_t)b * nct + t] : -1e30f;
        float ps = (t < nct) ? psum[(size_t)b * nct + t] : 0.f;
        float gm = waveReduceMax(pm);
        float s = waveReduceSum(ps * __expf(pm - gm));
        if (t == 0) {
            float ls = gm + __logf(s);
            shls = ls;
            int tg = tgt[b];
            cerow[b] = -(bfu(lrow[tg]) - ls);
        }
    }
    // meanwhile: stage pcat row into LDS as f32
    for (int c = t; c < LDP / 8; c += 256) {
        u32x4 raw = __builtin_nontemporal_load(&((const u32x4*)prow)[c]);
        const u16* rp = (const u16*)&raw;
        #pragma unroll
        for (int k = 0; k < 8; ++k) PC[c * 8 + k] = bfu(rp[k]);
    }
    __syncthreads();
    float ls = shls;

    for (int c = t; c < NC5 / 8; c += 256) {
        u32x4 raw = __builtin_nontemporal_load(&((const u32x4*)lrow)[c]);
        const u16* rp = (const u16*)&raw;
        f32x4 p0, p1;
        #pragma unroll
        for (int k = 0; k < 4; ++k) p0[k] = __expf(bfu(rp[k]) - ls);
        #pragma unroll
        for (int k = 0; k < 4; ++k) p1[k] = __expf(bfu(rp[4 + k]) - ls);
        __builtin_nontemporal_store(p0, &((f32x4*)orow)[c * 2]);
        __builtin_nontemporal_store(p1, &((f32x4*)orow)[c * 2 + 1]);
        union { u16 u[8]; uint4 v; } pk;
        #pragma unroll
        for (int k = 0; k < 4; ++k) pk.u[k] = f2bf(p0[k]);
        #pragma unroll
        for (int k = 0; k < 4; ++k) pk.u[4 + k] = f2bf(p1[k]);
        ((uint4*)P5)[c] = pk.v;
    }
    __syncthreads();

    auto softmax_seg = [&](int off, int C) {
        float m = -1e30f;
        for (int c = t; c < C; c += 256) m = fmaxf(m, PC[off + c]);
        m = blockReduceMax(m, sh);
        float s = 0.f;
        for (int c = t; c < C; c += 256) { float e = __expf(PC[off + c] - m); PC[off + c] = e; s += e; }
        s = blockReduceSum(s, sh);
        float inv = 1.0f / s;
        for (int c = t; c < C; c += 256) PC[off + c] *= inv;
    };
    softmax_seg(0, NC1);
    softmax_seg(20, NC2);
    softmax_seg(120, NC3);
    softmax_seg(620, NC4);
    __syncthreads();

    {   // jsd45: agg p5 (fan 5) vs p4
        float klpm = 0.f, klqm = 0.f;
        for (int g = t; g < NC4; g += 256) {
            float qv = 0.f;
            #pragma unroll
            for (int f = 0; f < 5; ++f) qv += bfu(P5[5 * g + f]);
            float pp = PC[620 + g];
            float mm = 0.5f * (qv + pp);
            float lm = __logf(mm + 1e-8f);
            klpm += qv * (__logf(qv + 1e-8f) - lm);
            klqm += pp * (__logf(pp + 1e-8f) - lm);
        }
        float tot = blockReduceSum(0.5f * (klpm + klqm), sh);
        if (t == 0) j45[b] = tot;
    }
    auto jsd_seg = [&](int childOff, int fan, int parentOff, int nPar, float* dst) {
        float klpm = 0.f, klqm = 0.f;
        for (int g = t; g < nPar; g += 256) {
            float qv = 0.f;
            for (int f = 0; f < fan; ++f) qv += PC[childOff + g * fan + f];
            float pp = PC[parentOff + g];
            float mm = 0.5f * (qv + pp);
            float lm = __logf(mm + 1e-8f);
            klpm += qv * (__logf(qv + 1e-8f) - lm);
            klqm += pp * (__logf(pp + 1e-8f) - lm);
        }
        float tot = blockReduceSum(0.5f * (klpm + klqm), sh);
        if (t == 0) dst[b] = tot;
    };
    jsd_seg(620, 4, 120, NC3, j34);
    jsd_seg(120, 5, 20, NC2, j23);
    jsd_seg(20, 5, 0, NC1, j12);
}

// ---------------- weight cosine terms (from normalized bf16 wb) ----------------

__global__ __launch_bounds__(64) void wcos_all(const u16* __restrict__ wb,
                                               float* __restrict__ c45, float* __restrict__ c34,
                                               float* __restrict__ c23, float* __restrict__ c12) {
    int g = blockIdx.x; int t = threadIdx.x;
    int pOff, cOff, fan, j; float* dst;
    if      (g < 2000) { pOff = 620; cOff = 2620; fan = 5; dst = c45; j = g; }
    else if (g < 2500) { pOff = 120; cOff = 620;  fan = 4; dst = c34; j = g - 2000; }
    else if (g < 2600) { pOff = 20;  cOff = 120;  fan = 5; dst = c23; j = g - 2500; }
    else               { pOff = 0;   cOff = 20;   fan = 5; dst = c12; j = g - 2600; }

    float hat[8] = {0, 0, 0, 0, 0, 0, 0, 0};
    for (int c = 0; c < fan; ++c) {
        const uint4 raw = ((const uint4*)(wb + (size_t)(cOff + j * fan + c) * FEAT))[t];
        const u16* rp = (const u16*)&raw;
        #pragma unroll
        for (int i = 0; i < 8; ++i) hat[i] += bfu(rp[i]);
    }
    float hs = 0.f;
    #pragma unroll
    for (int i = 0; i < 8; ++i) hs += hat[i] * hat[i];
    hs = waveReduceSum(hs);
    float hinv = 1.0f / fmaxf(sqrtf(hs), 1e-12f);
    const uint4 praw = ((const uint4*)(wb + (size_t)(pOff + j) * FEAT))[t];
    const u16* pp = (const u16*)&praw;
    float dot = 0.f;
    #pragma unroll
    for (int i = 0; i < 8; ++i) dot += bfu(pp[i]) * hat[i];
    dot = waveReduceSum(dot);
    if (t == 0) dst[j] = dot * hinv;
}

__global__ __launch_bounds__(256) void finalize(const float* __restrict__ ce, const float* __restrict__ j45,
                                                const float* __restrict__ j34, const float* __restrict__ j23,
                                                const float* __restrict__ j12, const float* __restrict__ c45,
                                                const float* __restrict__ c34, const float* __restrict__ c23,
                                                const float* __restrict__ c12, float* __restrict__ lossOut) {
    __shared__ float sh[4];
    auto meanArr = [&](const float* a, int n) {
        float s = 0.f;
        for (int i = threadIdx.x; i < n; i += 256) s += a[i];
        s = blockReduceSum(s, sh);
        return s / n;
    };
    float loss = meanArr(ce, BATCH);
    loss += meanArr(j45, BATCH) + meanArr(j34, BATCH) + meanArr(j23, BATCH) + meanArr(j12, BATCH);
    loss -= meanArr(c45, NC4) + meanArr(c34, NC3) + meanArr(c23, NC2) + meanArr(c12, NC1);
    if (threadIdx.x == 0) *lossOut = loss;
}

// ---------------- launch ----------------

extern "C" void kernel_launch(void* const* d_in, const int* in_sizes, int n_in,
                              void* d_out, int out_size, void* d_ws, size_t ws_size,
                              hipStream_t stream) {
    const float* x  = (const float*)d_in[0];
    const int*   tg = (const int*)d_in[1];
    const float* W1 = (const float*)d_in[2];  const float* b1 = (const float*)d_in[3];
    const float* W2 = (const float*)d_in[4];  const float* b2 = (const float*)d_in[5];
    const float* W3 = (const float*)d_in[6];  const float* b3 = (const float*)d_in[7];
    const float* W4 = (const float*)d_in[8];  const float* b4 = (const float*)d_in[9];
    const float* W5 = (const float*)d_in[10]; const float* b5 = (const float*)d_in[11];
    float* out = (float*)d_out;

    const int NCT = 40;   // l5 column tiles (by = 10..49)

    char* ws = (char*)d_ws;
    size_t off = 0;
    auto alloc = [&](size_t bytes) { void* p = ws + off; off = (off + bytes + 255) & ~(size_t)255; return p; };
    u16*   xb      = (u16*)alloc((size_t)BATCH * FEAT * 2);
    u16*   wb      = (u16*)alloc((size_t)NTOT * FEAT * 2);
    float* biascat = (float*)alloc((size_t)NTOT * 4);
    u16*   pcat    = (u16*)alloc((size_t)BATCH * LDP * 2);
    u16*   l5b     = (u16*)alloc((size_t)BATCH * NC5 * 2);
    float* pmax    = (float*)alloc((size_t)BATCH * NCT * 4);
    float* psum    = (float*)alloc((size_t)BATCH * NCT * 4);
    float* cerow   = (float*)alloc((size_t)BATCH * 4);
    float* j45     = (float*)alloc((size_t)BATCH * 4);
    float* j34     = (float*)alloc((size_t)BATCH * 4);
    float* j23     = (float*)alloc((size_t)BATCH * 4);
    float* j12     = (float*)alloc((size_t)BATCH * 4);
    float* c45     = (float*)alloc((size_t)NC4 * 4);
    float* c34     = (float*)alloc((size_t)NC3 * 4);
    float* c23     = (float*)alloc((size_t)NC2 * 4);
    float* c12     = (float*)alloc((size_t)NC1 * 4);

    prep<<<WN_BLOCKS + CAST_BLOCKS, 256, 0, stream>>>(x, xb, W1, b1, W2, b2, W3, b3, W4, b4, W5, b5,
                                                      wb, biascat);

    gemm_all<<<dim3(BATCH / BM, (NTOT + BN - 1) / BN), 512, 0, stream>>>(
        xb, wb, biascat, pcat, l5b, pmax, psum);

    probs_all<<<BATCH, 256, 0, stream>>>(l5b, out, pcat, pmax, psum, NCT, tg, cerow,
                                         j12, j23, j34, j45);

    wcos_all<<<NC4 + NC3 + NC2 + NC1, 64, 0, stream>>>(wb, c45, c34, c23, c12);

    finalize<<<1, 256, 0, stream>>>(cerow, j45, j34, j23, j12, c45, c34, c23, c12,
                                    out + (size_t)BATCH * NC5);
}

// Round 9
// 434.434 us; speedup vs baseline: 1.0532x; 1.0532x over previous
//
#include <hip/hip_runtime.h>
#include <hip/hip_bf16.h>
#include <stdint.h>

typedef unsigned short u16;
typedef __bf16 bf16x8 __attribute__((ext_vector_type(8)));
typedef float f32x4 __attribute__((ext_vector_type(4)));
typedef unsigned int u32x4 __attribute__((ext_vector_type(4)));

#define FEAT 512
#define BATCH 8192
#define NC1 20
#define NC2 100
#define NC3 500
#define NC4 2000
#define NC5 10000
#define NCAT 2620
#define LDP 2624          // padded leading dim for pcat (16B-clean bf16 rows)
#define NTOT 12620
#define WN_BLOCKS 3155    // ceil(12620 / 4) wnorm blocks (4 rows x 64 lanes)
#define CAST_BLOCKS 2048  // 8192*512/8/256

__device__ inline u16 f2bf(float f) {
    unsigned int u = __builtin_bit_cast(unsigned int, f);
    unsigned int r = (u + 0x7FFFu + ((u >> 16) & 1u)) >> 16;
    return (u16)r;
}
__device__ inline float bfu(u16 u) {
    return __builtin_bit_cast(float, (unsigned int)u << 16);
}

__device__ inline float waveReduceSum(float v) {
    #pragma unroll
    for (int off = 32; off > 0; off >>= 1) v += __shfl_xor(v, off);
    return v;
}
__device__ inline float waveReduceMax(float v) {
    #pragma unroll
    for (int off = 32; off > 0; off >>= 1) v = fmaxf(v, __shfl_xor(v, off));
    return v;
}
__device__ inline float blockReduceSum(float v, float* sh) {
    int t = threadIdx.x;
    v = waveReduceSum(v);
    __syncthreads();
    if ((t & 63) == 0) sh[t >> 6] = v;
    __syncthreads();
    return sh[0] + sh[1] + sh[2] + sh[3];
}
__device__ inline float blockReduceMax(float v, float* sh) {
    int t = threadIdx.x;
    v = waveReduceMax(v);
    __syncthreads();
    if ((t & 63) == 0) sh[t >> 6] = v;
    __syncthreads();
    return fmaxf(fmaxf(sh[0], sh[1]), fmaxf(sh[2], sh[3]));
}

__device__ inline void gload16(const void* g, void* l) {
    __builtin_amdgcn_global_load_lds((const __attribute__((address_space(1))) void*)g,
                                     (__attribute__((address_space(3))) void*)l, 16, 0, 0);
}

// ---------------- prep: cast x to bf16 + l2-normalize all weights ----------------

__global__ __launch_bounds__(256) void prep(const float* __restrict__ x, u16* __restrict__ xb,
                                            const float* __restrict__ W1, const float* __restrict__ b1,
                                            const float* __restrict__ W2, const float* __restrict__ b2,
                                            const float* __restrict__ W3, const float* __restrict__ b3,
                                            const float* __restrict__ W4, const float* __restrict__ b4,
                                            const float* __restrict__ W5, const float* __restrict__ b5,
                                            u16* __restrict__ wb, float* __restrict__ biascat) {
    int bid = blockIdx.x;
    if (bid < WN_BLOCKS) {
        int r = bid * 4 + (threadIdx.x >> 6);
        if (r >= NTOT) return;
        int t = threadIdx.x & 63;
        const float* W; const float* b; int lr;
        if      (r < 20)   { W = W1; b = b1; lr = r; }
        else if (r < 120)  { W = W2; b = b2; lr = r - 20; }
        else if (r < 620)  { W = W3; b = b3; lr = r - 120; }
        else if (r < 2620) { W = W4; b = b4; lr = r - 620; }
        else               { W = W5; b = b5; lr = r - 2620; }
        const float* p = W + (size_t)lr * FEAT + t * 8;
        float v[8]; float ss = 0.f;
        #pragma unroll
        for (int j = 0; j < 8; ++j) { v[j] = p[j]; ss += v[j] * v[j]; }
        ss = waveReduceSum(ss);
        float inv = 1.0f / fmaxf(sqrtf(ss), 1e-12f);
        union { u16 u[8]; uint4 q; } o;
        #pragma unroll
        for (int j = 0; j < 8; ++j) o.u[j] = f2bf(v[j] * inv);
        ((uint4*)(wb + (size_t)r * FEAT))[t] = o.q;
        if (t == 0) biascat[r] = b[lr];
    } else {
        int i = (bid - WN_BLOCKS) * 256 + threadIdx.x;
        const float* p = x + (size_t)i * 8;
        union { u16 u[8]; uint4 v; } o;
        #pragma unroll
        for (int j = 0; j < 8; ++j) o.u[j] = f2bf(p[j]);
        ((uint4*)xb)[i] = o.v;
    }
}

// ---------------- GEMM over all 12620 columns ----------------
// m97 geometry: 128x128 tile, BK=64, 4 waves (2x2), wave tile 64x64
// (acc = 64 VGPR), dbuf LDS 2x32 KB -> 2 blocks/CU, XOR-swizzled LDS via
// global_load_lds w16, transposed mfma (lane holds 4 consecutive output cols),
// counted-vmcnt raw-barrier pipeline (32 MFMA per barrier-pair), setprio.
// cols < NCAT -> pcat; cols >= NCAT -> l5b + softmax partials (by >= 20).

#define BM 128
#define BN 128
#define BK 64
#define KITERS (FEAT / BK)          // 8
#define NCT 79                      // l5 col tiles: by = 20..98

__global__ __launch_bounds__(256, 2) void gemm_all(const u16* __restrict__ A, const u16* __restrict__ Bw,
                                                   const float* __restrict__ bias,
                                                   u16* __restrict__ pcat, u16* __restrict__ l5b,
                                                   float* __restrict__ pmax, float* __restrict__ psum) {
    __shared__ u16 sAB[2][2 * BM * BK];        // 2 x 32 KB double buffer
    const int t = threadIdx.x;
    const int lane = t & 63, wid = t >> 6;
    const int lane15 = lane & 15, q = lane >> 4;
    const int wrow = wid >> 1, wcol = wid & 1;

    // XCD-aware bijective swizzle (nwg = 64*99 = 6336, %8 == 0)
    int nwg = gridDim.x * gridDim.y;
    int lid = blockIdx.y * gridDim.x + blockIdx.x;
    int cpx = nwg >> 3;
    int swz = (lid & 7) * cpx + (lid >> 3);
    int bx = swz % gridDim.x, by = swz / gridDim.x;
    const int r0 = bx * BM, c0 = by * BN;

    f32x4 acc[4][4];
    #pragma unroll
    for (int m = 0; m < 4; ++m)
        #pragma unroll
        for (int n = 0; n < 4; ++n) acc[m][n] = f32x4{0.f, 0.f, 0.f, 0.f};

    // stage: 2048 16B chunks (A: 0..1023, B: 1024..2047), 8 per thread.
    // chunk c: row = (c & 1023) >> 3, blk = c & 7, swizzled source k.
    auto stage = [&](int kt, int buf) {
        char* base = (char*)sAB[buf];
        #pragma unroll
        for (int p = 0; p < 8; ++p) {
            int c = p * 256 + t;                // 0..2047
            int cc = c & 1023;
            int row = cc >> 3, blk = cc & 7;
            int srck = 8 * (blk ^ (row & 7));   // swizzled source k (bf16 idx)
            const u16* g;
            if (c < 1024) {
                g = A + (size_t)(r0 + row) * FEAT + kt + srck;
            } else {
                int brow = c0 + row; if (brow >= NTOT) brow = NTOT - 1;
                g = Bw + (size_t)brow * FEAT + kt + srck;
            }
            gload16(g, base + (size_t)c * 16);
        }
    };

    stage(0, 0);            // 8 loads/thread in flight
    stage(BK, 1);           // 16 in flight
    for (int ki = 0; ki < KITERS; ++ki) {
        if (ki + 1 < KITERS) { asm volatile("s_waitcnt vmcnt(8)" ::: "memory"); }
        else                 { asm volatile("s_waitcnt vmcnt(0)" ::: "memory"); }
        __builtin_amdgcn_sched_barrier(0);
        __builtin_amdgcn_s_barrier();
        __builtin_amdgcn_sched_barrier(0);
        char* sAb = (char*)sAB[ki & 1];
        char* sBb = sAb + BM * BK * 2;          // +16 KB
        #pragma unroll
        for (int ks = 0; ks < 2; ++ks) {
            const int kko = ks * 4 + q;
            bf16x8 af[4], bv[4];
            #pragma unroll
            for (int m = 0; m < 4; ++m) {
                int row = wrow * 64 + m * 16 + lane15;
                af[m] = *reinterpret_cast<const bf16x8*>(sAb + row * 128 + 16 * (kko ^ (row & 7)));
            }
            #pragma unroll
            for (int n = 0; n < 4; ++n) {
                int row = wcol * 64 + n * 16 + lane15;
                bv[n] = *reinterpret_cast<const bf16x8*>(sBb + row * 128 + 16 * (kko ^ (row & 7)));
            }
            __builtin_amdgcn_s_setprio(1);
            #pragma unroll
            for (int m = 0; m < 4; ++m)
                #pragma unroll
                for (int n = 0; n < 4; ++n)
                    acc[m][n] = __builtin_amdgcn_mfma_f32_16x16x32_bf16(bv[n], af[m], acc[m][n], 0, 0, 0);
            __builtin_amdgcn_s_setprio(0);
        }
        __builtin_amdgcn_sched_barrier(0);
        __builtin_amdgcn_s_barrier();
        __builtin_amdgcn_sched_barrier(0);
        if (ki + 2 < KITERS) stage((ki + 2) * BK, ki & 1);
    }

    // transposed D layout: lane holds row = r0+wrow*64+m*16+lane15,
    // cols cb..cb+3 with cb = c0+wcol*64+n*16+q*4 (fragment never spans
    // the pcat/l5 boundary since NCAT % 4 == 0; NTOT % 4 == 0)
    bool vld[4], svld[4]; int cb[4];
    #pragma unroll
    for (int n = 0; n < 4; ++n) {
        cb[n] = c0 + wcol * 64 + n * 16 + q * 4;
        vld[n] = (cb[n] < NTOT);
        svld[n] = vld[n] && (cb[n] >= NCAT);
        if (vld[n]) {
            float b0 = bias[cb[n]], b1 = bias[cb[n] + 1], b2 = bias[cb[n] + 2], b3 = bias[cb[n] + 3];
            #pragma unroll
            for (int m = 0; m < 4; ++m) {
                acc[m][n][0] += b0; acc[m][n][1] += b1;
                acc[m][n][2] += b2; acc[m][n][3] += b3;
            }
        }
    }

    if (by >= 20) {   // col-tile overlaps the l5 region: emit softmax partials
        float* fmx = (float*)sAB;            // [128][2] row-max per wcol
        float* fsm = fmx + 256;              // [128][2] row-sumexp per wcol
        float bm[4];
        #pragma unroll
        for (int m = 0; m < 4; ++m) {
            float v = -1e30f;
            #pragma unroll
            for (int n = 0; n < 4; ++n)
                if (svld[n]) {
                    #pragma unroll
                    for (int j = 0; j < 4; ++j) v = fmaxf(v, acc[m][n][j]);
                }
            v = fmaxf(v, __shfl_xor(v, 16));
            v = fmaxf(v, __shfl_xor(v, 32));
            bm[m] = v;
        }
        if (lane < 16) {
            #pragma unroll
            for (int m = 0; m < 4; ++m)
                fmx[(wrow * 64 + m * 16 + lane15) * 2 + wcol] = bm[m];
        }
        __syncthreads();
        #pragma unroll
        for (int m = 0; m < 4; ++m) {
            int row = wrow * 64 + m * 16 + lane15;
            bm[m] = fmaxf(fmx[row * 2], fmx[row * 2 + 1]);
        }
        float sm[4];
        #pragma unroll
        for (int m = 0; m < 4; ++m) {
            float s = 0.f;
            #pragma unroll
            for (int n = 0; n < 4; ++n)
                if (svld[n]) {
                    #pragma unroll
                    for (int j = 0; j < 4; ++j) s += __expf(acc[m][n][j] - bm[m]);
                }
            s += __shfl_xor(s, 16);
            s += __shfl_xor(s, 32);
            sm[m] = s;
        }
        if (lane < 16) {
            #pragma unroll
            for (int m = 0; m < 4; ++m)
                fsm[(wrow * 64 + m * 16 + lane15) * 2 + wcol] = sm[m];
        }
        __syncthreads();
        if (t < 128) {
            float m2 = fmaxf(fmx[t * 2], fmx[t * 2 + 1]);
            float s2 = fsm[t * 2] + fsm[t * 2 + 1];
            size_t idx = (size_t)(r0 + t) * NCT + (by - 20);
            pmax[idx] = m2;
            psum[idx] = s2;
        }
    }

    // store bf16 as uint2 (4 consecutive cols per lane), routed per region
    #pragma unroll
    for (int m = 0; m < 4; ++m) {
        int row = r0 + wrow * 64 + m * 16 + lane15;
        #pragma unroll
        for (int n = 0; n < 4; ++n) {
            if (vld[n]) {
                union { u16 u[4]; uint2 v; } pk;
                #pragma unroll
                for (int j = 0; j < 4; ++j) pk.u[j] = f2bf(acc[m][n][j]);
                u16* dst = (cb[n] < NCAT)
                    ? &pcat[(size_t)row * LDP + cb[n]]
                    : &l5b[(size_t)row * NC5 + (cb[n] - NCAT)];
                *reinterpret_cast<uint2*>(dst) = pk.v;
            }
        }
    }
}

// ---------------- fused LSE + CE + probabilities + all JSDs (block per row) ----------------

__global__ __launch_bounds__(256) void probs_all(const u16* __restrict__ l5b, float* __restrict__ out,
                                                 const u16* __restrict__ pcat,
                                                 const float* __restrict__ pmax, const float* __restrict__ psum,
                                                 const int* __restrict__ tgt,
                                                 float* __restrict__ cerow,
                                                 float* __restrict__ j12, float* __restrict__ j23,
                                                 float* __restrict__ j34, float* __restrict__ j45) {
    __shared__ u16 P5[NC5];
    __shared__ float PC[LDP];
    __shared__ float sh[4];
    __shared__ float shls;
    int b = blockIdx.x, t = threadIdx.x;
    float* orow = out + (size_t)b * NC5;
    const u16* lrow = l5b + (size_t)b * NC5;
    const u16* prow = pcat + (size_t)b * LDP;

    // wave 0: reduce the per-coltile partials into the row LSE
    if (t < 64) {
        const float* pm = pmax + (size_t)b * NCT;
        const float* ps = psum + (size_t)b * NCT;
        float gm = -1e30f;
        for (int i = t; i < NCT; i += 64) gm = fmaxf(gm, pm[i]);
        gm = waveReduceMax(gm);
        float s = 0.f;
        for (int i = t; i < NCT; i += 64) s += ps[i] * __expf(pm[i] - gm);
        s = waveReduceSum(s);
        if (t == 0) {
            float ls = gm + __logf(s);
            shls = ls;
            int tg = tgt[b];
            cerow[b] = -(bfu(lrow[tg]) - ls);
        }
    }
    // meanwhile: stage pcat row into LDS as f32
    for (int c = t; c < LDP / 8; c += 256) {
        u32x4 raw = __builtin_nontemporal_load(&((const u32x4*)prow)[c]);
        const u16* rp = (const u16*)&raw;
        #pragma unroll
        for (int k = 0; k < 8; ++k) PC[c * 8 + k] = bfu(rp[k]);
    }
    __syncthreads();
    float ls = shls;

    for (int c = t; c < NC5 / 8; c += 256) {
        u32x4 raw = __builtin_nontemporal_load(&((const u32x4*)lrow)[c]);
        const u16* rp = (const u16*)&raw;
        f32x4 p0, p1;
        #pragma unroll
        for (int k = 0; k < 4; ++k) p0[k] = __expf(bfu(rp[k]) - ls);
        #pragma unroll
        for (int k = 0; k < 4; ++k) p1[k] = __expf(bfu(rp[4 + k]) - ls);
        __builtin_nontemporal_store(p0, &((f32x4*)orow)[c * 2]);
        __builtin_nontemporal_store(p1, &((f32x4*)orow)[c * 2 + 1]);
        union { u16 u[8]; uint4 v; } pk;
        #pragma unroll
        for (int k = 0; k < 4; ++k) pk.u[k] = f2bf(p0[k]);
        #pragma unroll
        for (int k = 0; k < 4; ++k) pk.u[4 + k] = f2bf(p1[k]);
        ((uint4*)P5)[c] = pk.v;
    }
    __syncthreads();

    auto softmax_seg = [&](int off, int C) {
        float m = -1e30f;
        for (int c = t; c < C; c += 256) m = fmaxf(m, PC[off + c]);
        m = blockReduceMax(m, sh);
        float s = 0.f;
        for (int c = t; c < C; c += 256) { float e = __expf(PC[off + c] - m); PC[off + c] = e; s += e; }
        s = blockReduceSum(s, sh);
        float inv = 1.0f / s;
        for (int c = t; c < C; c += 256) PC[off + c] *= inv;
    };
    softmax_seg(0, NC1);
    softmax_seg(20, NC2);
    softmax_seg(120, NC3);
    softmax_seg(620, NC4);
    __syncthreads();

    {   // jsd45: agg p5 (fan 5) vs p4
        float klpm = 0.f, klqm = 0.f;
        for (int g = t; g < NC4; g += 256) {
            float qv = 0.f;
            #pragma unroll
            for (int f = 0; f < 5; ++f) qv += bfu(P5[5 * g + f]);
            float pp = PC[620 + g];
            float mm = 0.5f * (qv + pp);
            float lm = __logf(mm + 1e-8f);
            klpm += qv * (__logf(qv + 1e-8f) - lm);
            klqm += pp * (__logf(pp + 1e-8f) - lm);
        }
        float tot = blockReduceSum(0.5f * (klpm + klqm), sh);
        if (t == 0) j45[b] = tot;
    }
    auto jsd_seg = [&](int childOff, int fan, int parentOff, int nPar, float* dst) {
        float klpm = 0.f, klqm = 0.f;
        for (int g = t; g < nPar; g += 256) {
            float qv = 0.f;
            for (int f = 0; f < fan; ++f) qv += PC[childOff + g * fan + f];
            float pp = PC[parentOff + g];
            float mm = 0.5f * (qv + pp);
            float lm = __logf(mm + 1e-8f);
            klpm += qv * (__logf(qv + 1e-8f) - lm);
            klqm += pp * (__logf(pp + 1e-8f) - lm);
        }
        float tot = blockReduceSum(0.5f * (klpm + klqm), sh);
        if (t == 0) dst[b] = tot;
    };
    jsd_seg(620, 4, 120, NC3, j34);
    jsd_seg(120, 5, 20, NC2, j23);
    jsd_seg(20, 5, 0, NC1, j12);
}

// ---------------- weight cosine terms (from normalized bf16 wb) ----------------

__global__ __launch_bounds__(64) void wcos_all(const u16* __restrict__ wb,
                                               float* __restrict__ c45, float* __restrict__ c34,
                                               float* __restrict__ c23, float* __restrict__ c12) {
    int g = blockIdx.x; int t = threadIdx.x;
    int pOff, cOff, fan, j; float* dst;
    if      (g < 2000) { pOff = 620; cOff = 2620; fan = 5; dst = c45; j = g; }
    else if (g < 2500) { pOff = 120; cOff = 620;  fan = 4; dst = c34; j = g - 2000; }
    else if (g < 2600) { pOff = 20;  cOff = 120;  fan = 5; dst = c23; j = g - 2500; }
    else               { pOff = 0;   cOff = 20;   fan = 5; dst = c12; j = g - 2600; }

    float hat[8] = {0, 0, 0, 0, 0, 0, 0, 0};
    for (int c = 0; c < fan; ++c) {
        const uint4 raw = ((const uint4*)(wb + (size_t)(cOff + j * fan + c) * FEAT))[t];
        const u16* rp = (const u16*)&raw;
        #pragma unroll
        for (int i = 0; i < 8; ++i) hat[i] += bfu(rp[i]);
    }
    float hs = 0.f;
    #pragma unroll
    for (int i = 0; i < 8; ++i) hs += hat[i] * hat[i];
    hs = waveReduceSum(hs);
    float hinv = 1.0f / fmaxf(sqrtf(hs), 1e-12f);
    const uint4 praw = ((const uint4*)(wb + (size_t)(pOff + j) * FEAT))[t];
    const u16* pp = (const u16*)&praw;
    float dot = 0.f;
    #pragma unroll
    for (int i = 0; i < 8; ++i) dot += bfu(pp[i]) * hat[i];
    dot = waveReduceSum(dot);
    if (t == 0) dst[j] = dot * hinv;
}

__global__ __launch_bounds__(256) void finalize(const float* __restrict__ ce, const float* __restrict__ j45,
                                                const float* __restrict__ j34, const float* __restrict__ j23,
                                                const float* __restrict__ j12, const float* __restrict__ c45,
                                                const float* __restrict__ c34, const float* __restrict__ c23,
                                                const float* __restrict__ c12, float* __restrict__ lossOut) {
    __shared__ float sh[4];
    auto meanArr = [&](const float* a, int n) {
        float s = 0.f;
        for (int i = threadIdx.x; i < n; i += 256) s += a[i];
        s = blockReduceSum(s, sh);
        return s / n;
    };
    float loss = meanArr(ce, BATCH);
    loss += meanArr(j45, BATCH) + meanArr(j34, BATCH) + meanArr(j23, BATCH) + meanArr(j12, BATCH);
    loss -= meanArr(c45, NC4) + meanArr(c34, NC3) + meanArr(c23, NC2) + meanArr(c12, NC1);
    if (threadIdx.x == 0) *lossOut = loss;
}

// ---------------- launch ----------------

extern "C" void kernel_launch(void* const* d_in, const int* in_sizes, int n_in,
                              void* d_out, int out_size, void* d_ws, size_t ws_size,
                              hipStream_t stream) {
    const float* x  = (const float*)d_in[0];
    const int*   tg = (const int*)d_in[1];
    const float* W1 = (const float*)d_in[2];  const float* b1 = (const float*)d_in[3];
    const float* W2 = (const float*)d_in[4];  const float* b2 = (const float*)d_in[5];
    const float* W3 = (const float*)d_in[6];  const float* b3 = (const float*)d_in[7];
    const float* W4 = (const float*)d_in[8];  const float* b4 = (const float*)d_in[9];
    const float* W5 = (const float*)d_in[10]; const float* b5 = (const float*)d_in[11];
    float* out = (float*)d_out;

    char* ws = (char*)d_ws;
    size_t off = 0;
    auto alloc = [&](size_t bytes) { void* p = ws + off; off = (off + bytes + 255) & ~(size_t)255; return p; };
    u16*   xb      = (u16*)alloc((size_t)BATCH * FEAT * 2);
    u16*   wb      = (u16*)alloc((size_t)NTOT * FEAT * 2);
    float* biascat = (float*)alloc((size_t)NTOT * 4);
    u16*   pcat    = (u16*)alloc((size_t)BATCH * LDP * 2);
    u16*   l5b     = (u16*)alloc((size_t)BATCH * NC5 * 2);
    float* pmax    = (float*)alloc((size_t)BATCH * NCT * 4);
    float* psum    = (float*)alloc((size_t)BATCH * NCT * 4);
    float* cerow   = (float*)alloc((size_t)BATCH * 4);
    float* j45     = (float*)alloc((size_t)BATCH * 4);
    float* j34     = (float*)alloc((size_t)BATCH * 4);
    float* j23     = (float*)alloc((size_t)BATCH * 4);
    float* j12     = (float*)alloc((size_t)BATCH * 4);
    float* c45     = (float*)alloc((size_t)NC4 * 4);
    float* c34     = (float*)alloc((size_t)NC3 * 4);
    float* c23     = (float*)alloc((size_t)NC2 * 4);
    float* c12     = (float*)alloc((size_t)NC1 * 4);

    prep<<<WN_BLOCKS + CAST_BLOCKS, 256, 0, stream>>>(x, xb, W1, b1, W2, b2, W3, b3, W4, b4, W5, b5,
                                                      wb, biascat);

    gemm_all<<<dim3(BATCH / BM, (NTOT + BN - 1) / BN), 256, 0, stream>>>(
        xb, wb, biascat, pcat, l5b, pmax, psum);

    probs_all<<<BATCH, 256, 0, stream>>>(l5b, out, pcat, pmax, psum, tg, cerow,
                                         j12, j23, j34, j45);

    wcos_all<<<NC4 + NC3 + NC2 + NC1, 64, 0, stream>>>(wb, c45, c34, c23, c12);

    finalize<<<1, 256, 0, stream>>>(cerow, j45, j34, j23, j12, c45, c34, c23, c12,
                                    out + (size_t)BATCH * NC5);
}

// Round 10
// 390.081 us; speedup vs baseline: 1.1730x; 1.1137x over previous
//
#include <hip/hip_runtime.h>
#include <hip/hip_bf16.h>
#include <stdint.h>

typedef unsigned short u16;
typedef __bf16 bf16x8 __attribute__((ext_vector_type(8)));
typedef float f32x4 __attribute__((ext_vector_type(4)));
typedef unsigned int u32x4 __attribute__((ext_vector_type(4)));

#define FEAT 512
#define BATCH 8192
#define NC1 20
#define NC2 100
#define NC3 500
#define NC4 2000
#define NC5 10000
#define NCAT 2620
#define LDP 2624          // padded leading dim for pcat (16B-clean bf16 rows)
#define NTOT 12620
#define NCT 40            // l5 col tiles (by = 10..49)
#define WN_BLOCKS 3155    // ceil(12620 / 4) wnorm blocks (4 rows x 64 lanes)
#define CAST_BLOCKS 2048  // 8192*512/8/256
#define NGRP 2620         // cosine groups total
#define WCOS_BLOCKS 655   // ceil(2620 / 4)

__device__ inline u16 f2bf(float f) {
    unsigned int u = __builtin_bit_cast(unsigned int, f);
    unsigned int r = (u + 0x7FFFu + ((u >> 16) & 1u)) >> 16;
    return (u16)r;
}
__device__ inline float bfu(u16 u) {
    return __builtin_bit_cast(float, (unsigned int)u << 16);
}

__device__ inline float waveReduceSum(float v) {
    #pragma unroll
    for (int off = 32; off > 0; off >>= 1) v += __shfl_xor(v, off);
    return v;
}
__device__ inline float waveReduceMax(float v) {
    #pragma unroll
    for (int off = 32; off > 0; off >>= 1) v = fmaxf(v, __shfl_xor(v, off));
    return v;
}
__device__ inline float blockReduceSum(float v, float* sh) {
    int t = threadIdx.x;
    v = waveReduceSum(v);
    __syncthreads();
    if ((t & 63) == 0) sh[t >> 6] = v;
    __syncthreads();
    return sh[0] + sh[1] + sh[2] + sh[3];
}
__device__ inline float blockReduceMax(float v, float* sh) {
    int t = threadIdx.x;
    v = waveReduceMax(v);
    __syncthreads();
    if ((t & 63) == 0) sh[t >> 6] = v;
    __syncthreads();
    return fmaxf(fmaxf(sh[0], sh[1]), fmaxf(sh[2], sh[3]));
}

__device__ inline void gload16(const void* g, void* l) {
    __builtin_amdgcn_global_load_lds((const __attribute__((address_space(1))) void*)g,
                                     (__attribute__((address_space(3))) void*)l, 16, 0, 0);
}

// ---------------- prep: cast x, l2-normalize all weights, AND wcos terms ----------------
// wcos part is independent of the wnorm output (renormalizes raw W itself),
// so it can live in the same launch and overlap.

__global__ __launch_bounds__(256) void prep(const float* __restrict__ x, u16* __restrict__ xb,
                                            const float* __restrict__ W1, const float* __restrict__ b1,
                                            const float* __restrict__ W2, const float* __restrict__ b2,
                                            const float* __restrict__ W3, const float* __restrict__ b3,
                                            const float* __restrict__ W4, const float* __restrict__ b4,
                                            const float* __restrict__ W5, const float* __restrict__ b5,
                                            u16* __restrict__ wb, float* __restrict__ biascat,
                                            float* __restrict__ c45, float* __restrict__ c34,
                                            float* __restrict__ c23, float* __restrict__ c12) {
    int bid = blockIdx.x;
    if (bid < WN_BLOCKS) {
        int r = bid * 4 + (threadIdx.x >> 6);
        if (r >= NTOT) return;
        int t = threadIdx.x & 63;
        const float* W; const float* b; int lr;
        if      (r < 20)   { W = W1; b = b1; lr = r; }
        else if (r < 120)  { W = W2; b = b2; lr = r - 20; }
        else if (r < 620)  { W = W3; b = b3; lr = r - 120; }
        else if (r < 2620) { W = W4; b = b4; lr = r - 620; }
        else               { W = W5; b = b5; lr = r - 2620; }
        const float* p = W + (size_t)lr * FEAT + t * 8;
        float v[8]; float ss = 0.f;
        #pragma unroll
        for (int j = 0; j < 8; ++j) { v[j] = p[j]; ss += v[j] * v[j]; }
        ss = waveReduceSum(ss);
        float inv = 1.0f / fmaxf(sqrtf(ss), 1e-12f);
        union { u16 u[8]; uint4 q; } o;
        #pragma unroll
        for (int j = 0; j < 8; ++j) o.u[j] = f2bf(v[j] * inv);
        ((uint4*)(wb + (size_t)r * FEAT))[t] = o.q;
        if (t == 0) biascat[r] = b[lr];
    } else if (bid < WN_BLOCKS + CAST_BLOCKS) {
        int i = (bid - WN_BLOCKS) * 256 + threadIdx.x;
        const float* p = x + (size_t)i * 8;
        union { u16 u[8]; uint4 v; } o;
        #pragma unroll
        for (int j = 0; j < 8; ++j) o.u[j] = f2bf(p[j]);
        ((uint4*)xb)[i] = o.v;
    } else {
        // weight-cosine terms: one wave per group, 4 groups per block
        int g = (bid - WN_BLOCKS - CAST_BLOCKS) * 4 + (threadIdx.x >> 6);
        if (g >= NGRP) return;
        int t = threadIdx.x & 63;
        const float* Wp; const float* Wc; int fan, j; float* dst;
        if      (g < 2000) { Wp = W4; Wc = W5; fan = 5; dst = c45; j = g; }
        else if (g < 2500) { Wp = W3; Wc = W4; fan = 4; dst = c34; j = g - 2000; }
        else if (g < 2600) { Wp = W2; Wc = W3; fan = 5; dst = c23; j = g - 2500; }
        else               { Wp = W1; Wc = W2; fan = 5; dst = c12; j = g - 2600; }

        float hat[8] = {0, 0, 0, 0, 0, 0, 0, 0};
        for (int c = 0; c < fan; ++c) {
            const float* cr = Wc + ((size_t)(j * fan + c)) * FEAT + t * 8;
            float v[8]; float ss = 0.f;
            #pragma unroll
            for (int i = 0; i < 8; ++i) { v[i] = cr[i]; ss += v[i] * v[i]; }
            ss = waveReduceSum(ss);
            float inv = 1.0f / fmaxf(sqrtf(ss), 1e-12f);
            #pragma unroll
            for (int i = 0; i < 8; ++i) hat[i] += v[i] * inv;
        }
        float hs = 0.f;
        #pragma unroll
        for (int i = 0; i < 8; ++i) hs += hat[i] * hat[i];
        hs = waveReduceSum(hs);
        float hinv = 1.0f / fmaxf(sqrtf(hs), 1e-12f);
        const float* pr = Wp + (size_t)j * FEAT + t * 8;
        float ps = 0.f, dot = 0.f;
        #pragma unroll
        for (int i = 0; i < 8; ++i) { float pv = pr[i]; ps += pv * pv; dot += pv * hat[i]; }
        ps = waveReduceSum(ps);
        dot = waveReduceSum(dot);
        if (t == 0) dst[j] = dot * hinv / fmaxf(sqrtf(ps), 1e-12f);
    }
}

// ---------------- GEMM over all 12620 columns (round-7 measured-best config) ----------------
// 256x256 tile, 8 waves (2x4), BK=64, double-buffered global_load_lds w16,
// XOR-swizzled LDS, transposed mfma (lane holds 4 consecutive output cols),
// counted-vmcnt raw-barrier pipeline (64 MFMA per barrier-pair), setprio.
// cols < NCAT -> pcat; cols >= NCAT -> l5b + softmax partials (by >= 10).

#define BM 256
#define BN 256
#define BK 64
#define KITERS (FEAT / BK)

__global__ __launch_bounds__(512, 2) void gemm_all(const u16* __restrict__ A, const u16* __restrict__ Bw,
                                                   const float* __restrict__ bias,
                                                   u16* __restrict__ pcat, u16* __restrict__ l5b,
                                                   float* __restrict__ pmax, float* __restrict__ psum) {
    __shared__ u16 sAB[2][2 * BM * BK];        // 2 x 64 KB double buffer
    const int t = threadIdx.x;
    const int lane = t & 63, wid = t >> 6;
    const int lane15 = lane & 15, q = lane >> 4;
    const int wr = wid >> 2, wcol = wid & 3;

    // XCD-aware bijective swizzle (nwg = 32*50 = 1600, %8 == 0)
    int nwg = gridDim.x * gridDim.y;
    int lid = blockIdx.y * gridDim.x + blockIdx.x;
    int cpx = nwg >> 3;
    int swz = (lid & 7) * cpx + (lid >> 3);
    int bx = swz % gridDim.x, by = swz / gridDim.x;
    const int r0 = bx * BM, c0 = by * BN;

    f32x4 acc[8][4];
    #pragma unroll
    for (int m = 0; m < 8; ++m)
        #pragma unroll
        for (int n = 0; n < 4; ++n) acc[m][n] = f32x4{0.f, 0.f, 0.f, 0.f};

    auto stage = [&](int kt, int buf) {
        char* base = (char*)sAB[buf];
        #pragma unroll
        for (int p = 0; p < 8; ++p) {
            int chunk = p * 512 + t;            // 0..4095 (16B each)
            int row = chunk >> 3, blk = chunk & 7;
            int srck = 8 * (blk ^ (row & 7));   // swizzled source k (bf16 idx)
            const u16* g;
            if (p < 4) {
                g = A + (size_t)(r0 + row) * FEAT + kt + srck;
            } else {
                int brow = c0 + (row - 256); if (brow >= NTOT) brow = NTOT - 1;
                g = Bw + (size_t)brow * FEAT + kt + srck;
            }
            gload16(g, base + (size_t)chunk * 16);
        }
    };

    stage(0, 0);            // 8 loads in flight
    stage(BK, 1);           // 16 in flight
    for (int ki = 0; ki < KITERS; ++ki) {
        if (ki + 1 < KITERS) { asm volatile("s_waitcnt vmcnt(8)" ::: "memory"); }
        else                 { asm volatile("s_waitcnt vmcnt(0)" ::: "memory"); }
        __builtin_amdgcn_sched_barrier(0);
        __builtin_amdgcn_s_barrier();
        __builtin_amdgcn_sched_barrier(0);
        char* sAb = (char*)sAB[ki & 1];
        char* sBb = sAb + BM * BK * 2;
        #pragma unroll
        for (int ks = 0; ks < 2; ++ks) {
            const int kko = ks * 4 + q;
            bf16x8 af[8], bv[4];
            #pragma unroll
            for (int m = 0; m < 8; ++m) {
                int row = wr * 128 + m * 16 + lane15;
                af[m] = *reinterpret_cast<const bf16x8*>(sAb + row * 128 + 16 * (kko ^ (row & 7)));
            }
            #pragma unroll
            for (int n = 0; n < 4; ++n) {
                int row = wcol * 64 + n * 16 + lane15;
                bv[n] = *reinterpret_cast<const bf16x8*>(sBb + row * 128 + 16 * (kko ^ (row & 7)));
            }
            __builtin_amdgcn_s_setprio(1);
            #pragma unroll
            for (int m = 0; m < 8; ++m)
                #pragma unroll
                for (int n = 0; n < 4; ++n)
                    acc[m][n] = __builtin_amdgcn_mfma_f32_16x16x32_bf16(bv[n], af[m], acc[m][n], 0, 0, 0);
            __builtin_amdgcn_s_setprio(0);
        }
        __builtin_amdgcn_sched_barrier(0);
        __builtin_amdgcn_s_barrier();
        __builtin_amdgcn_sched_barrier(0);
        if (ki + 2 < KITERS) stage((ki + 2) * BK, ki & 1);
    }

    // transposed D layout: lane holds row = r0+wr*128+m*16+lane15,
    // cols cb..cb+3 with cb = c0+wcol*64+n*16+q*4 (fragment never spans
    // the pcat/l5 boundary since NCAT % 4 == 0)
    bool vld[4], svld[4]; int cb[4];
    #pragma unroll
    for (int n = 0; n < 4; ++n) {
        cb[n] = c0 + wcol * 64 + n * 16 + q * 4;
        vld[n] = (cb[n] < NTOT);
        svld[n] = vld[n] && (cb[n] >= NCAT);
        if (vld[n]) {
            float b0 = bias[cb[n]], b1 = bias[cb[n] + 1], b2 = bias[cb[n] + 2], b3 = bias[cb[n] + 3];
            #pragma unroll
            for (int m = 0; m < 8; ++m) {
                acc[m][n][0] += b0; acc[m][n][1] += b1;
                acc[m][n][2] += b2; acc[m][n][3] += b3;
            }
        }
    }

    if (by >= 10) {   // this col-tile overlaps the l5 region: emit softmax partials
        float* fmx = (float*)sAB;            // [256][4] row-max per wcol
        float* fsm = fmx + 1024;             // [256][4] row-sumexp per wcol
        float bm[8];
        #pragma unroll
        for (int m = 0; m < 8; ++m) {
            float v = -1e30f;
            #pragma unroll
            for (int n = 0; n < 4; ++n)
                if (svld[n]) {
                    #pragma unroll
                    for (int j = 0; j < 4; ++j) v = fmaxf(v, acc[m][n][j]);
                }
            v = fmaxf(v, __shfl_xor(v, 16));
            v = fmaxf(v, __shfl_xor(v, 32));
            bm[m] = v;
        }
        if (lane < 16) {
            #pragma unroll
            for (int m = 0; m < 8; ++m)
                fmx[(wr * 128 + m * 16 + lane15) * 4 + wcol] = bm[m];
        }
        __syncthreads();
        #pragma unroll
        for (int m = 0; m < 8; ++m) {
            int row = wr * 128 + m * 16 + lane15;
            bm[m] = fmaxf(fmaxf(fmx[row * 4], fmx[row * 4 + 1]),
                          fmaxf(fmx[row * 4 + 2], fmx[row * 4 + 3]));
        }
        float sm[8];
        #pragma unroll
        for (int m = 0; m < 8; ++m) {
            float s = 0.f;
            #pragma unroll
            for (int n = 0; n < 4; ++n)
                if (svld[n]) {
                    #pragma unroll
                    for (int j = 0; j < 4; ++j) s += __expf(acc[m][n][j] - bm[m]);
                }
            s += __shfl_xor(s, 16);
            s += __shfl_xor(s, 32);
            sm[m] = s;
        }
        if (lane < 16) {
            #pragma unroll
            for (int m = 0; m < 8; ++m)
                fsm[(wr * 128 + m * 16 + lane15) * 4 + wcol] = sm[m];
        }
        __syncthreads();
        if (t < 256) {
            float m4 = fmaxf(fmaxf(fmx[t * 4], fmx[t * 4 + 1]), fmaxf(fmx[t * 4 + 2], fmx[t * 4 + 3]));
            float s4 = fsm[t * 4] + fsm[t * 4 + 1] + fsm[t * 4 + 2] + fsm[t * 4 + 3];
            size_t idx = (size_t)(r0 + t) * NCT + (by - 10);
            pmax[idx] = m4;
            psum[idx] = s4;
        }
    }

    // store bf16 as uint2 (4 consecutive cols per lane), routed per region
    #pragma unroll
    for (int m = 0; m < 8; ++m) {
        int row = r0 + wr * 128 + m * 16 + lane15;
        #pragma unroll
        for (int n = 0; n < 4; ++n) {
            if (vld[n]) {
                union { u16 u[4]; uint2 v; } pk;
                #pragma unroll
                for (int j = 0; j < 4; ++j) pk.u[j] = f2bf(acc[m][n][j]);
                u16* dst = (cb[n] < NCAT)
                    ? &pcat[(size_t)row * LDP + cb[n]]
                    : &l5b[(size_t)row * NC5 + (cb[n] - NCAT)];
                *reinterpret_cast<uint2*>(dst) = pk.v;
            }
        }
    }
}

// ---------------- fused LSE + CE + probabilities + all JSDs (block per row) ----------------

__global__ __launch_bounds__(256) void probs_all(const u16* __restrict__ l5b, float* __restrict__ out,
                                                 const u16* __restrict__ pcat,
                                                 const float* __restrict__ pmax, const float* __restrict__ psum,
                                                 const int* __restrict__ tgt,
                                                 float* __restrict__ cerow,
                                                 float* __restrict__ j12, float* __restrict__ j23,
                                                 float* __restrict__ j34, float* __restrict__ j45) {
    __shared__ u16 P5[NC5];
    __shared__ float PC[LDP];
    __shared__ float sh[4];
    __shared__ float shls;
    int b = blockIdx.x, t = threadIdx.x;
    float* orow = out + (size_t)b * NC5;
    const u16* lrow = l5b + (size_t)b * NC5;
    const u16* prow = pcat + (size_t)b * LDP;

    // wave 0: reduce the per-coltile partials into the row LSE
    if (t < 64) {
        float pm = (t < NCT) ? pmax[(size_t)b * NCT + t] : -1e30f;
        float ps = (t < NCT) ? psum[(size_t)b * NCT + t] : 0.f;
        float gm = waveReduceMax(pm);
        float s = waveReduceSum(ps * __expf(pm - gm));
        if (t == 0) {
            float ls = gm + __logf(s);
            shls = ls;
            int tg = tgt[b];
            cerow[b] = -(bfu(lrow[tg]) - ls);
        }
    }
    // meanwhile: stage pcat row into LDS as f32
    for (int c = t; c < LDP / 8; c += 256) {
        u32x4 raw = __builtin_nontemporal_load(&((const u32x4*)prow)[c]);
        const u16* rp = (const u16*)&raw;
        #pragma unroll
        for (int k = 0; k < 8; ++k) PC[c * 8 + k] = bfu(rp[k]);
    }
    __syncthreads();
    float ls = shls;

    for (int c = t; c < NC5 / 8; c += 256) {
        u32x4 raw = __builtin_nontemporal_load(&((const u32x4*)lrow)[c]);
        const u16* rp = (const u16*)&raw;
        f32x4 p0, p1;
        #pragma unroll
        for (int k = 0; k < 4; ++k) p0[k] = __expf(bfu(rp[k]) - ls);
        #pragma unroll
        for (int k = 0; k < 4; ++k) p1[k] = __expf(bfu(rp[4 + k]) - ls);
        __builtin_nontemporal_store(p0, &((f32x4*)orow)[c * 2]);
        __builtin_nontemporal_store(p1, &((f32x4*)orow)[c * 2 + 1]);
        union { u16 u[8]; uint4 v; } pk;
        #pragma unroll
        for (int k = 0; k < 4; ++k) pk.u[k] = f2bf(p0[k]);
        #pragma unroll
        for (int k = 0; k < 4; ++k) pk.u[4 + k] = f2bf(p1[k]);
        ((uint4*)P5)[c] = pk.v;
    }
    __syncthreads();

    auto softmax_seg = [&](int off, int C) {
        float m = -1e30f;
        for (int c = t; c < C; c += 256) m = fmaxf(m, PC[off + c]);
        m = blockReduceMax(m, sh);
        float s = 0.f;
        for (int c = t; c < C; c += 256) { float e = __expf(PC[off + c] - m); PC[off + c] = e; s += e; }
        s = blockReduceSum(s, sh);
        float inv = 1.0f / s;
        for (int c = t; c < C; c += 256) PC[off + c] *= inv;
    };
    softmax_seg(0, NC1);
    softmax_seg(20, NC2);
    softmax_seg(120, NC3);
    softmax_seg(620, NC4);
    __syncthreads();

    {   // jsd45: agg p5 (fan 5) vs p4
        float klpm = 0.f, klqm = 0.f;
        for (int g = t; g < NC4; g += 256) {
            float qv = 0.f;
            #pragma unroll
            for (int f = 0; f < 5; ++f) qv += bfu(P5[5 * g + f]);
            float pp = PC[620 + g];
            float mm = 0.5f * (qv + pp);
            float lm = __logf(mm + 1e-8f);
            klpm += qv * (__logf(qv + 1e-8f) - lm);
            klqm += pp * (__logf(pp + 1e-8f) - lm);
        }
        float tot = blockReduceSum(0.5f * (klpm + klqm), sh);
        if (t == 0) j45[b] = tot;
    }
    auto jsd_seg = [&](int childOff, int fan, int parentOff, int nPar, float* dst) {
        float klpm = 0.f, klqm = 0.f;
        for (int g = t; g < nPar; g += 256) {
            float qv = 0.f;
            for (int f = 0; f < fan; ++f) qv += PC[childOff + g * fan + f];
            float pp = PC[parentOff + g];
            float mm = 0.5f * (qv + pp);
            float lm = __logf(mm + 1e-8f);
            klpm += qv * (__logf(qv + 1e-8f) - lm);
            klqm += pp * (__logf(pp + 1e-8f) - lm);
        }
        float tot = blockReduceSum(0.5f * (klpm + klqm), sh);
        if (t == 0) dst[b] = tot;
    };
    jsd_seg(620, 4, 120, NC3, j34);
    jsd_seg(120, 5, 20, NC2, j23);
    jsd_seg(20, 5, 0, NC1, j12);
}

__global__ __launch_bounds__(256) void finalize(const float* __restrict__ ce, const float* __restrict__ j45,
                                                const float* __restrict__ j34, const float* __restrict__ j23,
                                                const float* __restrict__ j12, const float* __restrict__ c45,
                                                const float* __restrict__ c34, const float* __restrict__ c23,
                                                const float* __restrict__ c12, float* __restrict__ lossOut) {
    __shared__ float sh[4];
    auto meanArr = [&](const float* a, int n) {
        float s = 0.f;
        for (int i = threadIdx.x; i < n; i += 256) s += a[i];
        s = blockReduceSum(s, sh);
        return s / n;
    };
    float loss = meanArr(ce, BATCH);
    loss += meanArr(j45, BATCH) + meanArr(j34, BATCH) + meanArr(j23, BATCH) + meanArr(j12, BATCH);
    loss -= meanArr(c45, NC4) + meanArr(c34, NC3) + meanArr(c23, NC2) + meanArr(c12, NC1);
    if (threadIdx.x == 0) *lossOut = loss;
}

// ---------------- launch ----------------

extern "C" void kernel_launch(void* const* d_in, const int* in_sizes, int n_in,
                              void* d_out, int out_size, void* d_ws, size_t ws_size,
                              hipStream_t stream) {
    const float* x  = (const float*)d_in[0];
    const int*   tg = (const int*)d_in[1];
    const float* W1 = (const float*)d_in[2];  const float* b1 = (const float*)d_in[3];
    const float* W2 = (const float*)d_in[4];  const float* b2 = (const float*)d_in[5];
    const float* W3 = (const float*)d_in[6];  const float* b3 = (const float*)d_in[7];
    const float* W4 = (const float*)d_in[8];  const float* b4 = (const float*)d_in[9];
    const float* W5 = (const float*)d_in[10]; const float* b5 = (const float*)d_in[11];
    float* out = (float*)d_out;

    char* ws = (char*)d_ws;
    size_t off = 0;
    auto alloc = [&](size_t bytes) { void* p = ws + off; off = (off + bytes + 255) & ~(size_t)255; return p; };
    u16*   xb      = (u16*)alloc((size_t)BATCH * FEAT * 2);
    u16*   wb      = (u16*)alloc((size_t)NTOT * FEAT * 2);
    float* biascat = (float*)alloc((size_t)NTOT * 4);
    u16*   pcat    = (u16*)alloc((size_t)BATCH * LDP * 2);
    u16*   l5b     = (u16*)alloc((size_t)BATCH * NC5 * 2);
    float* pmax    = (float*)alloc((size_t)BATCH * NCT * 4);
    float* psum    = (float*)alloc((size_t)BATCH * NCT * 4);
    float* cerow   = (float*)alloc((size_t)BATCH * 4);
    float* j45     = (float*)alloc((size_t)BATCH * 4);
    float* j34     = (float*)alloc((size_t)BATCH * 4);
    float* j23     = (float*)alloc((size_t)BATCH * 4);
    float* j12     = (float*)alloc((size_t)BATCH * 4);
    float* c45     = (float*)alloc((size_t)NC4 * 4);
    float* c34     = (float*)alloc((size_t)NC3 * 4);
    float* c23     = (float*)alloc((size_t)NC2 * 4);
    float* c12     = (float*)alloc((size_t)NC1 * 4);

    prep<<<WN_BLOCKS + CAST_BLOCKS + WCOS_BLOCKS, 256, 0, stream>>>(
        x, xb, W1, b1, W2, b2, W3, b3, W4, b4, W5, b5, wb, biascat, c45, c34, c23, c12);

    gemm_all<<<dim3(BATCH / BM, (NTOT + BN - 1) / BN), 512, 0, stream>>>(
        xb, wb, biascat, pcat, l5b, pmax, psum);

    probs_all<<<BATCH, 256, 0, stream>>>(l5b, out, pcat, pmax, psum, tg, cerow,
                                         j12, j23, j34, j45);

    finalize<<<1, 256, 0, stream>>>(cerow, j45, j34, j23, j12, c45, c34, c23, c12,
                                    out + (size_t)BATCH * NC5);
}